// Round 9
// baseline (7219.955 us; speedup 1.0000x reference)
//
#include <hip/hip_runtime.h>

#define N_NODES 16384
#define N_EDGES 524288
#define BAND_I 16      // rows per block
#define CHUNK_J 1024   // 256 threads x 4 j per chunk
#define N_CHUNKS 8     // chunks per block; 2 blocks per i-band
// grid = 1024 bands * 2 = 2048 persistent blocks

typedef float f32x4 __attribute__((ext_vector_type(4)));

// ---------------- kernel 1: scatter-add neighbor features ----------------
__global__ void scatter_kernel(const int* __restrict__ eidx,
                               const float* __restrict__ x,
                               float* __restrict__ agg) {
    int e = blockIdx.x * blockDim.x + threadIdx.x;
    if (e >= N_EDGES) return;
    int s = eidx[e];            // src row
    int t = eidx[N_EDGES + e];  // tgt row
    float f0 = x[s * 3 + 0];
    float f1 = x[s * 3 + 1];
    float f2 = x[s * 3 + 2];
    atomicAdd(&agg[t * 3 + 0], f0);
    atomicAdd(&agg[t * 3 + 1], f1);
    atomicAdd(&agg[t * 3 + 2], f2);
}

// ---------------- kernel 2: GIN MLP per node -> h [N,16] ----------------
__global__ void mlp_kernel(const float* __restrict__ x,
                           const float* __restrict__ agg,
                           const float* __restrict__ W1,
                           const float* __restrict__ b1,
                           const float* __restrict__ W2,
                           const float* __restrict__ b2,
                           const float* __restrict__ eps_p,
                           float* __restrict__ h) {
    int n = blockIdx.x * blockDim.x + threadIdx.x;
    if (n >= N_NODES) return;
    float se = 1.0f + eps_p[0];
    float z0 = se * x[n * 3 + 0] + agg[n * 3 + 0];
    float z1 = se * x[n * 3 + 1] + agg[n * 3 + 1];
    float z2 = se * x[n * 3 + 2] + agg[n * 3 + 2];
    float h1[16];
#pragma unroll
    for (int j = 0; j < 16; ++j) {
        float a = b1[j];
        a += z0 * W1[0 * 16 + j];
        a += z1 * W1[1 * 16 + j];
        a += z2 * W1[2 * 16 + j];
        h1[j] = fmaxf(a, 0.0f);
    }
    float4* h4 = (float4*)&h[n * 16];
#pragma unroll
    for (int oq = 0; oq < 4; ++oq) {
        float4 o;
        float* op = (float*)&o;
#pragma unroll
        for (int c = 0; c < 4; ++c) {
            int oo = oq * 4 + c;
            float a = b2[oo];
#pragma unroll
            for (int j = 0; j < 16; ++j) a += h1[j] * W2[j * 16 + oo];
            op[c] = fmaxf(a, 0.0f);
        }
        h4[oq] = o;
    }
}

// ---------------- kernel 3: out[i][j] = dot(h[i], h[j]) ----------------
// Persistent blocks, spill-proof: 2048 blocks x 256 threads, VGPR capped at
// 128 via __launch_bounds__(256,4). hi staged once (1 KB LDS, one barrier);
// 8 j-chunks of 1024 j with no inner barriers. The hj transpose uses 16
// NAMED f32x4 registers from 16 named loads (R8's hj[16] array inside the
// loop went to scratch: VGPR=256 + 5.7 GB scratch FETCH). Store drain paid
// once per block (8 blocks/CU sequential) instead of once per 128KB tile.
__global__ __launch_bounds__(256, 4) void pairwise_kernel(const float* __restrict__ h,
                                                          float* __restrict__ out) {
    __shared__ float hi[BAND_I * 16];   // 1 KB
    const int band = blockIdx.x >> 1;
    const int half = blockIdx.x & 1;
    const int i0 = band * BAND_I;
    const int tid = threadIdx.x;

    // stage hi panel: 16 rows x 4 f32x4 = 64 f32x4
    if (tid < BAND_I * 4) {
        ((f32x4*)hi)[tid] = ((const f32x4*)h)[(size_t)i0 * 4 + tid];
    }
    __syncthreads();

    const f32x4* hg = (const f32x4*)h;
    f32x4* out4 = (f32x4*)out;
    const int jcol = tid * 4;   // this thread's 4 j within the chunk

#pragma unroll 1
    for (int c = 0; c < N_CHUNKS; ++c) {
        const int jbase = (half * N_CHUNKS + c) * CHUNK_J + jcol;
        const size_t jb = (size_t)jbase * 4;

        // 16 named loads: q<row><quad>, rows a..d = jbase+0..3, quads 0..3
        f32x4 qa0 = hg[jb +  0], qa1 = hg[jb +  1], qa2 = hg[jb +  2], qa3 = hg[jb +  3];
        f32x4 qb0 = hg[jb +  4], qb1 = hg[jb +  5], qb2 = hg[jb +  6], qb3 = hg[jb +  7];
        f32x4 qc0 = hg[jb +  8], qc1 = hg[jb +  9], qc2 = hg[jb + 10], qc3 = hg[jb + 11];
        f32x4 qd0 = hg[jb + 12], qd1 = hg[jb + 13], qd2 = hg[jb + 14], qd3 = hg[jb + 15];

        // k-major transpose, all-static: hj<k>[jj] = q<jj><k/4>[k%4]
        f32x4 hj0  = (f32x4){qa0.x, qb0.x, qc0.x, qd0.x};
        f32x4 hj1  = (f32x4){qa0.y, qb0.y, qc0.y, qd0.y};
        f32x4 hj2  = (f32x4){qa0.z, qb0.z, qc0.z, qd0.z};
        f32x4 hj3  = (f32x4){qa0.w, qb0.w, qc0.w, qd0.w};
        f32x4 hj4  = (f32x4){qa1.x, qb1.x, qc1.x, qd1.x};
        f32x4 hj5  = (f32x4){qa1.y, qb1.y, qc1.y, qd1.y};
        f32x4 hj6  = (f32x4){qa1.z, qb1.z, qc1.z, qd1.z};
        f32x4 hj7  = (f32x4){qa1.w, qb1.w, qc1.w, qd1.w};
        f32x4 hj8  = (f32x4){qa2.x, qb2.x, qc2.x, qd2.x};
        f32x4 hj9  = (f32x4){qa2.y, qb2.y, qc2.y, qd2.y};
        f32x4 hj10 = (f32x4){qa2.z, qb2.z, qc2.z, qd2.z};
        f32x4 hj11 = (f32x4){qa2.w, qb2.w, qc2.w, qd2.w};
        f32x4 hj12 = (f32x4){qa3.x, qb3.x, qc3.x, qd3.x};
        f32x4 hj13 = (f32x4){qa3.y, qb3.y, qc3.y, qd3.y};
        f32x4 hj14 = (f32x4){qa3.z, qb3.z, qc3.z, qd3.z};
        f32x4 hj15 = (f32x4){qa3.w, qb3.w, qc3.w, qd3.w};

        const size_t ob = (size_t)i0 * (N_NODES / 4) + (size_t)(jbase >> 2);
#pragma unroll
        for (int r = 0; r < BAND_I; ++r) {
            const f32x4* hr = (const f32x4*)&hi[r * 16];
            f32x4 a0 = hr[0], a1 = hr[1], a2 = hr[2], a3 = hr[3];
            f32x4 acc = a0.x * hj0;
            acc += a0.y * hj1;
            acc += a0.z * hj2;
            acc += a0.w * hj3;
            acc += a1.x * hj4;
            acc += a1.y * hj5;
            acc += a1.z * hj6;
            acc += a1.w * hj7;
            acc += a2.x * hj8;
            acc += a2.y * hj9;
            acc += a2.z * hj10;
            acc += a2.w * hj11;
            acc += a3.x * hj12;
            acc += a3.y * hj13;
            acc += a3.z * hj14;
            acc += a3.w * hj15;
            __builtin_nontemporal_store(acc, &out4[ob + (size_t)r * (N_NODES / 4)]);
        }
    }
}

extern "C" void kernel_launch(void* const* d_in, const int* in_sizes, int n_in,
                              void* d_out, int out_size, void* d_ws, size_t ws_size,
                              hipStream_t stream) {
    const float* node_feats = (const float*)d_in[0];
    const int*   edge_idx   = (const int*)d_in[1];
    const float* W1         = (const float*)d_in[2];
    const float* b1         = (const float*)d_in[3];
    const float* W2         = (const float*)d_in[4];
    const float* b2         = (const float*)d_in[5];
    const float* eps        = (const float*)d_in[6];
    float* out = (float*)d_out;

    // workspace layout: agg [N*3 floats] at 0, h [N*16 floats] at 256 KB
    float* agg = (float*)d_ws;
    float* h   = (float*)((char*)d_ws + 262144);

    hipMemsetAsync(agg, 0, N_NODES * 3 * sizeof(float), stream);
    scatter_kernel<<<N_EDGES / 256, 256, 0, stream>>>(edge_idx, node_feats, agg);
    mlp_kernel<<<N_NODES / 256, 256, 0, stream>>>(node_feats, agg, W1, b1, W2, b2, eps, h);

    pairwise_kernel<<<2048, 256, 0, stream>>>(h, out);
}

// Round 10
// 350.955 us; speedup vs baseline: 20.5723x; 20.5723x over previous
//
#include <hip/hip_runtime.h>

#define N_NODES 16384
#define N_EDGES 524288
#define BAND_I 64      // rows per block
#define TILE_J 2048    // 512 threads x 4 j
// grid = (16384/64) * (16384/2048) = 256 * 8 = 2048 blocks

typedef float f32x4 __attribute__((ext_vector_type(4)));

// ---------------- kernel 1: scatter-add neighbor features ----------------
__global__ void scatter_kernel(const int* __restrict__ eidx,
                               const float* __restrict__ x,
                               float* __restrict__ agg) {
    int e = blockIdx.x * blockDim.x + threadIdx.x;
    if (e >= N_EDGES) return;
    int s = eidx[e];            // src row
    int t = eidx[N_EDGES + e];  // tgt row
    float f0 = x[s * 3 + 0];
    float f1 = x[s * 3 + 1];
    float f2 = x[s * 3 + 2];
    atomicAdd(&agg[t * 3 + 0], f0);
    atomicAdd(&agg[t * 3 + 1], f1);
    atomicAdd(&agg[t * 3 + 2], f2);
}

// ---------------- kernel 2: GIN MLP per node -> h [N,16] ----------------
__global__ void mlp_kernel(const float* __restrict__ x,
                           const float* __restrict__ agg,
                           const float* __restrict__ W1,
                           const float* __restrict__ b1,
                           const float* __restrict__ W2,
                           const float* __restrict__ b2,
                           const float* __restrict__ eps_p,
                           float* __restrict__ h) {
    int n = blockIdx.x * blockDim.x + threadIdx.x;
    if (n >= N_NODES) return;
    float se = 1.0f + eps_p[0];
    float z0 = se * x[n * 3 + 0] + agg[n * 3 + 0];
    float z1 = se * x[n * 3 + 1] + agg[n * 3 + 1];
    float z2 = se * x[n * 3 + 2] + agg[n * 3 + 2];
    float h1[16];
#pragma unroll
    for (int j = 0; j < 16; ++j) {
        float a = b1[j];
        a += z0 * W1[0 * 16 + j];
        a += z1 * W1[1 * 16 + j];
        a += z2 * W1[2 * 16 + j];
        h1[j] = fmaxf(a, 0.0f);
    }
    float4* h4 = (float4*)&h[n * 16];
#pragma unroll
    for (int oq = 0; oq < 4; ++oq) {
        float4 o;
        float* op = (float*)&o;
#pragma unroll
        for (int c = 0; c < 4; ++c) {
            int oo = oq * 4 + c;
            float a = b2[oo];
#pragma unroll
            for (int j = 0; j < 16; ++j) a += h1[j] * W2[j * 16 + oo];
            op[c] = fmaxf(a, 0.0f);
        }
        h4[oq] = o;
    }
}

// ---------------- kernel 3: out[i][j] = dot(h[i], h[j]) ----------------
// Barrier-free long-lived blocks: 2048 blocks x 512 threads, 64 rows x 2048
// cols each. hj = 16 NAMED f32x4 (all indices static -> registers; R5/R8/R9
// died of scratch spill from runtime-indexed arrays / over-tight
// launch_bounds). hi rows are read with UNIFORM addresses straight from
// L2-resident h (scalar/broadcast loads, SGPR operands) -> no LDS, no
// __syncthreads, no forced vmcnt(0) drains. Per block-row the 8 waves store
// 8 KB contiguous (NT); endpgm drain paid once per 512 KB block.
__global__ __launch_bounds__(512) void pairwise_kernel(const float* __restrict__ h,
                                                       float* __restrict__ out) {
    const int i0 = (blockIdx.x >> 3) * BAND_I;
    const int jt = blockIdx.x & 7;
    const int tid = threadIdx.x;
    const int jbase = jt * TILE_J + tid * 4;

    const f32x4* hg = (const f32x4*)h;
    const size_t jb = (size_t)jbase * 4;

    // 16 named loads: q<row><quad>, rows a..d = jbase+0..3, quads 0..3
    f32x4 qa0 = hg[jb +  0], qa1 = hg[jb +  1], qa2 = hg[jb +  2], qa3 = hg[jb +  3];
    f32x4 qb0 = hg[jb +  4], qb1 = hg[jb +  5], qb2 = hg[jb +  6], qb3 = hg[jb +  7];
    f32x4 qc0 = hg[jb +  8], qc1 = hg[jb +  9], qc2 = hg[jb + 10], qc3 = hg[jb + 11];
    f32x4 qd0 = hg[jb + 12], qd1 = hg[jb + 13], qd2 = hg[jb + 14], qd3 = hg[jb + 15];

    // k-major transpose, all-static: hj<k> = { h[ja][k], h[jb][k], h[jc][k], h[jd][k] }
    f32x4 hj0  = (f32x4){qa0.x, qb0.x, qc0.x, qd0.x};
    f32x4 hj1  = (f32x4){qa0.y, qb0.y, qc0.y, qd0.y};
    f32x4 hj2  = (f32x4){qa0.z, qb0.z, qc0.z, qd0.z};
    f32x4 hj3  = (f32x4){qa0.w, qb0.w, qc0.w, qd0.w};
    f32x4 hj4  = (f32x4){qa1.x, qb1.x, qc1.x, qd1.x};
    f32x4 hj5  = (f32x4){qa1.y, qb1.y, qc1.y, qd1.y};
    f32x4 hj6  = (f32x4){qa1.z, qb1.z, qc1.z, qd1.z};
    f32x4 hj7  = (f32x4){qa1.w, qb1.w, qc1.w, qd1.w};
    f32x4 hj8  = (f32x4){qa2.x, qb2.x, qc2.x, qd2.x};
    f32x4 hj9  = (f32x4){qa2.y, qb2.y, qc2.y, qd2.y};
    f32x4 hj10 = (f32x4){qa2.z, qb2.z, qc2.z, qd2.z};
    f32x4 hj11 = (f32x4){qa2.w, qb2.w, qc2.w, qd2.w};
    f32x4 hj12 = (f32x4){qa3.x, qb3.x, qc3.x, qd3.x};
    f32x4 hj13 = (f32x4){qa3.y, qb3.y, qc3.y, qd3.y};
    f32x4 hj14 = (f32x4){qa3.z, qb3.z, qc3.z, qd3.z};
    f32x4 hj15 = (f32x4){qa3.w, qb3.w, qc3.w, qd3.w};

    f32x4* out4 = (f32x4*)out;
    const size_t obase = (size_t)i0 * (N_NODES / 4) + (size_t)(jbase >> 2);

#pragma unroll 4
    for (int r = 0; r < BAND_I; ++r) {
        // uniform address (i0, r wave-uniform) -> scalar/broadcast loads
        const f32x4* hr = (const f32x4*)&h[(size_t)(i0 + r) * 16];
        f32x4 a0 = hr[0], a1 = hr[1], a2 = hr[2], a3 = hr[3];
        f32x4 acc = a0.x * hj0;
        acc += a0.y * hj1;
        acc += a0.z * hj2;
        acc += a0.w * hj3;
        acc += a1.x * hj4;
        acc += a1.y * hj5;
        acc += a1.z * hj6;
        acc += a1.w * hj7;
        acc += a2.x * hj8;
        acc += a2.y * hj9;
        acc += a2.z * hj10;
        acc += a2.w * hj11;
        acc += a3.x * hj12;
        acc += a3.y * hj13;
        acc += a3.z * hj14;
        acc += a3.w * hj15;
        __builtin_nontemporal_store(acc, &out4[obase + (size_t)r * (N_NODES / 4)]);
    }
}

extern "C" void kernel_launch(void* const* d_in, const int* in_sizes, int n_in,
                              void* d_out, int out_size, void* d_ws, size_t ws_size,
                              hipStream_t stream) {
    const float* node_feats = (const float*)d_in[0];
    const int*   edge_idx   = (const int*)d_in[1];
    const float* W1         = (const float*)d_in[2];
    const float* b1         = (const float*)d_in[3];
    const float* W2         = (const float*)d_in[4];
    const float* b2         = (const float*)d_in[5];
    const float* eps        = (const float*)d_in[6];
    float* out = (float*)d_out;

    // workspace layout: agg [N*3 floats] at 0, h [N*16 floats] at 256 KB
    float* agg = (float*)d_ws;
    float* h   = (float*)((char*)d_ws + 262144);

    hipMemsetAsync(agg, 0, N_NODES * 3 * sizeof(float), stream);
    scatter_kernel<<<N_EDGES / 256, 256, 0, stream>>>(edge_idx, node_feats, agg);
    mlp_kernel<<<N_NODES / 256, 256, 0, stream>>>(node_feats, agg, W1, b1, W2, b2, eps, h);

    pairwise_kernel<<<2048, 512, 0, stream>>>(h, out);
}